// Round 1
// baseline (74.740 us; speedup 1.0000x reference)
//
#include <hip/hip_runtime.h>

// Problem constants (from reference setup_inputs)
#define BB 16
#define SS 2048
#define EE 128
#define WW 128
#define VV 7
#define WE (WW * EE) // 16384

// math: logit[b] = out_b + sum_o out_w[o]*fc_b[o]
//                 + sum_{e,k} emb[tok(b, last_b-127+k)][e] * v[e*128+k]
//        v[i]   = sum_o out_w[o] * fc_w[o*WE + i]
//
// R6 restructure: k1 is now a PURE fc_w stream (no x-scan, no dot, one
// barrier); k2 becomes 16 blocks (one per batch) doing scan+gather+dot
// against the 64 KB v vector. Kernel boundary carries v only.
//
// K1, block c (of 256): owns i-slice e = c>>1, k in [64*(c&1), +64).
//   Parks a 128x64 fc_w slab (32 KB) in registers, reduces over o via LDS,
//   writes 64 contiguous floats of v. Nothing else.
__global__ __launch_bounds__(256) void k1_v(const float* __restrict__ fc_w,
                                            const float* __restrict__ out_w,
                                            float* __restrict__ v) {
    __shared__ float red[16][64]; // o-group partials of the v slice

    const int c = blockIdx.x;
    const int t = threadIdx.x;
    const int lane = t & 63;
    const int w = t >> 6;
    const int e = c >> 1;
    const int k0 = (c & 1) * 64;

    // fc_w slab loads: 8 independent float4 per thread (32 KB/block in flight).
    const int oo = lane >> 4; // 0..3
    const int kq = lane & 15; // k-quad
    const float* fbase = fc_w + (size_t)e * WW + k0 + kq * 4;
    float4 f[8];
    float ow[8];
#pragma unroll
    for (int it = 0; it < 8; ++it) {
        const int o = w * 32 + it * 4 + oo;
        f[it] = *reinterpret_cast<const float4*>(fbase + (size_t)o * WE);
        ow[it] = out_w[o];
    }

    float4 acc = make_float4(0.f, 0.f, 0.f, 0.f);
#pragma unroll
    for (int it = 0; it < 8; ++it) {
        acc.x += ow[it] * f[it].x;
        acc.y += ow[it] * f[it].y;
        acc.z += ow[it] * f[it].z;
        acc.w += ow[it] * f[it].w;
    }
    *reinterpret_cast<float4*>(&red[w * 4 + oo][kq * 4]) = acc;
    __syncthreads();

    if (t < 64) {
        float s = 0.f;
#pragma unroll
        for (int g = 0; g < 16; ++g) s += red[g][t];
        v[(size_t)e * WW + k0 + t] = s; // coalesced 256 B per block
    }
}

// K2, block b (of 16): scan x[b] -> last; gather 128-token window; dot
// emb-window against v; add bias; write out[b].
__global__ __launch_bounds__(256) void k2_dot(const int* __restrict__ x,
                                              const float* __restrict__ emb,
                                              const float* __restrict__ v,
                                              const float* __restrict__ fc_b,
                                              const float* __restrict__ out_w,
                                              const float* __restrict__ out_b,
                                              float* __restrict__ out) {
    __shared__ float embS[8 * EE]; // rows 0..6 = emb, row 7 = zeros (left-pad)
    __shared__ int winTok[WW];
    __shared__ int cntW[4];
    __shared__ float wsum[4];

    const int b = blockIdx.x;
    const int t = threadIdx.x;
    const int lane = t & 63;
    const int w = t >> 6;
    const int* xb = x + b * SS;

    // Stage emb table (+ zero pad row): 1024 floats, 4 per thread.
    {
        const int f0 = t * 4;
#pragma unroll
        for (int j = 0; j < 4; ++j) {
            const int fi = f0 + j;
            embS[fi] = (fi < VV * EE) ? emb[fi] : 0.f;
        }
    }

    // Non-pad count: thread t covers 8 tokens (2x int4, coalesced 2 KB/wave).
    const int4* xq = reinterpret_cast<const int4*>(xb);
    const int4 q0 = xq[t * 2];
    const int4 q1 = xq[t * 2 + 1];
    int cnt = (q0.x != 0) + (q0.y != 0) + (q0.z != 0) + (q0.w != 0)
            + (q1.x != 0) + (q1.y != 0) + (q1.z != 0) + (q1.w != 0);
#pragma unroll
    for (int off = 32; off; off >>= 1) cnt += __shfl_down(cnt, off);
    if (lane == 0) cntW[w] = cnt;
    __syncthreads();
    const int last = cntW[0] + cntW[1] + cntW[2] + cntW[3] - 1;

    // Gather the 128-token causal window (tok 7 -> zero emb row for j<0).
    if (t < WW) {
        const int j = last - (WW - 1) + t;
        winTok[t] = (j >= 0) ? xb[j] : VV;
    }
    __syncthreads();

    // Bias partial on threads 0..127: sum_o out_w[o]*fc_b[o].
    float val = (t < EE) ? out_w[t] * fc_b[t] : 0.f;

    // Dot: thread owns (e = t>>1, k-half = t&1), 128 FMAs.
    // embS reads are uniform-row per half-wave (broadcast, conflict-free).
    const int e = t >> 1;
    const int kh = t & 1;
    const float4* vb4 = reinterpret_cast<const float4*>(v + e * WW + kh * 64);
    const int* wt = winTok + kh * 64;
#pragma unroll
    for (int k4 = 0; k4 < 16; ++k4) {
        const float4 vv = vb4[k4];
        val += embS[wt[k4 * 4 + 0] * EE + e] * vv.x;
        val += embS[wt[k4 * 4 + 1] * EE + e] * vv.y;
        val += embS[wt[k4 * 4 + 2] * EE + e] * vv.z;
        val += embS[wt[k4 * 4 + 3] * EE + e] * vv.w;
    }

    // Block reduction: wave shuffle -> LDS -> thread 0.
#pragma unroll
    for (int off = 32; off; off >>= 1) val += __shfl_down(val, off);
    if (lane == 0) wsum[w] = val;
    __syncthreads();
    if (t == 0) out[b] = wsum[0] + wsum[1] + wsum[2] + wsum[3] + out_b[0];
}

extern "C" void kernel_launch(void* const* d_in, const int* in_sizes, int n_in,
                              void* d_out, int out_size, void* d_ws, size_t ws_size,
                              hipStream_t stream) {
    const int* x = (const int*)d_in[0];
    const float* emb = (const float*)d_in[1];
    const float* fc_w = (const float*)d_in[2];
    const float* fc_b = (const float*)d_in[3];
    const float* out_w = (const float*)d_in[4];
    const float* out_b = (const float*)d_in[5];
    float* v = (float*)d_ws; // 16384 floats = 64 KB scratch
    float* out = (float*)d_out;

    k1_v<<<256, 256, 0, stream>>>(fc_w, out_w, v);
    k2_dot<<<16, 256, 0, stream>>>(x, emb, v, fc_b, out_w, out_b, out);
}